// Round 12
// baseline (1364.562 us; speedup 1.0000x reference)
//
#include <hip/hip_runtime.h>
#include <hip/hip_bf16.h>
#include <math.h>

#define N_NODES 50000
#define N_EDGES 200000
#define N_GRAPH 1024
#define HC      128
#define NFC     256
#define NLAYER  5
#define NFFC    512

typedef short bf16x8 __attribute__((ext_vector_type(8)));
typedef float f4v    __attribute__((ext_vector_type(4)));
typedef __attribute__((address_space(1))) const unsigned int gu32;
typedef __attribute__((address_space(3))) unsigned int su32;

__device__ __forceinline__ float ssp_f(float x) {
  float e = __expf(-fabsf(x));
  return fmaxf(x, 0.0f) + __logf(1.0f + e) - 0.69314718055994530942f;
}
__device__ __forceinline__ float tanh_f(float x) {
  float e = __expf(2.0f * fabsf(x));
  float t = 1.0f - 2.0f * __builtin_amdgcn_rcpf(e + 1.0f);
  return copysignf(t, x);
}
__device__ __forceinline__ unsigned short f2bf(float x) {
  __bf16 b = (__bf16)x;
  return __builtin_bit_cast(unsigned short, b);
}
__device__ __forceinline__ float bf2f(unsigned short u) {
  return (float)__builtin_bit_cast(__bf16, u);
}

// XOR 16B-slot swizzle (write and read must both use these).
__device__ __forceinline__ int swzA(int row, int col) {   // 128-short pitch
  return (row << 7) + (((col >> 3) ^ (row & 7)) << 3) + (col & 7);
}
__device__ __forceinline__ int swzT(int row, int col) {   // 256-short pitch
  return (row << 8) + (((col >> 3) ^ (row & 7)) << 3) + (col & 7);
}

// ---------------------------------------------------------------------------
__global__ void zero_kernel(float4* __restrict__ p, int n4) {
  int i = blockIdx.x * blockDim.x + threadIdx.x;
  if (i < n4) p[i] = make_float4(0.f, 0.f, 0.f, 0.f);
}
__global__ void zeroi_kernel(int* __restrict__ p, int n) {
  int i = blockIdx.x * blockDim.x + threadIdx.x;
  if (i < n) p[i] = 0;
}

// ---- dst-sort infrastructure ----------------------------------------------
__global__ void hist_kernel(const int* __restrict__ ei, int* __restrict__ deg) {
  int e = blockIdx.x * blockDim.x + threadIdx.x;
  if (e < N_EDGES) atomicAdd(&deg[ei[N_EDGES + e]], 1);
}
__global__ void scan1_kernel(const int* __restrict__ deg, int* __restrict__ excl,
                             int* __restrict__ bsum, int n) {
  __shared__ int buf[256];
  const int tid = threadIdx.x;
  const int i = blockIdx.x * 256 + tid;
  int v = (i < n) ? deg[i] : 0;
  buf[tid] = v;
  __syncthreads();
  for (int s = 1; s < 256; s <<= 1) {
    int t = (tid >= s) ? buf[tid - s] : 0;
    __syncthreads();
    buf[tid] += t;
    __syncthreads();
  }
  if (i < n) excl[i] = buf[tid] - v;
  if (tid == 255) bsum[blockIdx.x] = buf[255];
}
__global__ void scan2_kernel(int* __restrict__ bsum, int nb) {
  __shared__ int buf[256];
  const int tid = threadIdx.x;
  int v = (tid < nb) ? bsum[tid] : 0;
  buf[tid] = v;
  __syncthreads();
  for (int s = 1; s < 256; s <<= 1) {
    int t = (tid >= s) ? buf[tid - s] : 0;
    __syncthreads();
    buf[tid] += t;
    __syncthreads();
  }
  if (tid < nb) bsum[tid] = buf[tid] - v;
}
__global__ void scan3_kernel(int* __restrict__ excl, const int* __restrict__ bsum, int n) {
  int i = blockIdx.x * 256 + threadIdx.x;
  if (i < n) excl[i] += bsum[blockIdx.x];
}
__global__ void perm_kernel(const int* __restrict__ ei, int* __restrict__ cursor,
                            int* __restrict__ perm) {
  int e = blockIdx.x * blockDim.x + threadIdx.x;
  if (e < N_EDGES) {
    int d = ei[N_EDGES + e];
    int p = atomicAdd(&cursor[d], 1);
    perm[p] = e;
  }
}
__global__ void eperm_kernel(const int* __restrict__ ei, const int* __restrict__ perm,
                             int* __restrict__ eiPs, int* __restrict__ eiPd) {
  int p = blockIdx.x * blockDim.x + threadIdx.x;
  if (p < N_EDGES) {
    int e = perm[p];
    eiPs[p] = ei[e];
    eiPd[p] = ei[N_EDGES + e];
  }
}

__global__ void wconv_kernel(const float* __restrict__ w,
                             unsigned short* __restrict__ hi, int n) {
  int i = blockIdx.x * blockDim.x + threadIdx.x;
  if (i < n) hi[i] = f2bf(w[i]);
}

__global__ void embed_kernel(const int* __restrict__ x, const float* __restrict__ pos,
                             const float* __restrict__ vert, const float* __restrict__ posw,
                             unsigned short* __restrict__ h) {
  int n = blockIdx.x;
  int c = threadIdx.x;            // 128 threads
  float v;
  if (c < 80) {
    v = vert[(size_t)x[n] * 80 + c];
  } else {
    int j = c - 80;
    v = pos[n*3+0]*posw[j*3+0] + pos[n*3+1]*posw[j*3+1] + pos[n*3+2]*posw[j*3+2];
  }
  h[(size_t)n*HC + c] = f2bf(v);
}

// ---------------------------------------------------------------------------
// Node update: 64-row tile (grid 782, 32KB LDS), B-prefetch. (r6 form)
__global__ __launch_bounds__(256, 4) void nodeup_kernel(
    float* __restrict__ agg,
    const unsigned short* __restrict__ L2h,
    const float* __restrict__ b2,
    const unsigned short* __restrict__ L3h,
    const float* __restrict__ b3,
    unsigned short* h)
{
  __shared__ unsigned short ldsS[64 * 256];   // swizzled; reused for ssp out

  const int tid  = threadIdx.x;
  const int m0   = blockIdx.x * 64;
  const int lane = tid & 63, wave = tid >> 6;
  const int quad = lane >> 4, l16 = lane & 15;
  const int wn = wave * 32;           // waves split N only
  const int r  = tid >> 2;            // 0..63
  const int cb2 = (tid & 3) * 64;     // 64-col chunk

  const bool mok = (m0 + r) < N_NODES;

  // stage agg row-chunk -> bf16 LDS, then zero it for the next layer
  if (mok) {
    const float* ap = agg + (size_t)(m0 + r) * NFC + cb2;
#pragma unroll
    for (int g = 0; g < 8; g++) {
      float4 v0 = *(const float4*)(ap + g*8);
      float4 v1 = *(const float4*)(ap + g*8 + 4);
      unsigned short th[8];
      th[0] = f2bf(v0.x); th[1] = f2bf(v0.y); th[2] = f2bf(v0.z); th[3] = f2bf(v0.w);
      th[4] = f2bf(v1.x); th[5] = f2bf(v1.y); th[6] = f2bf(v1.z); th[7] = f2bf(v1.w);
      *(bf16x8*)&ldsS[swzT(r, cb2 + g*8)] = *(bf16x8*)th;
    }
    float4* zp = (float4*)(agg + (size_t)(m0 + r) * NFC + cb2);
    const float4 z4 = make_float4(0.f, 0.f, 0.f, 0.f);
#pragma unroll
    for (int g = 0; g < 16; g++) zp[g] = z4;
  } else {
    const bf16x8 zb = {0, 0, 0, 0, 0, 0, 0, 0};
#pragma unroll
    for (int g = 0; g < 8; g++) *(bf16x8*)&ldsS[swzT(r, cb2 + g*8)] = zb;
  }

  const f4v zf = {0.f, 0.f, 0.f, 0.f};
  f4v acc[4][2];
#pragma unroll
  for (int i = 0; i < 4; i++) { acc[i][0] = zf; acc[i][1] = zf; }

  // prefetch GEMM1 B group 0 (independent of LDS)
  bf16x8 bn[2];
#pragma unroll
  for (int nt = 0; nt < 2; nt++)
    bn[nt] = *(const bf16x8*)&L2h[(size_t)(wn + nt*16 + l16) * NFC + quad*8];

  __syncthreads();   // #1

  // GEMM1: out = agg @ L2^T  (64 MFMA / wave)
  for (int kki = 0; kki < 8; kki++) {
    bf16x8 bc[2] = {bn[0], bn[1]};
    if (kki < 7) {
#pragma unroll
      for (int nt = 0; nt < 2; nt++)
        bn[nt] = *(const bf16x8*)&L2h[(size_t)(wn + nt*16 + l16) * NFC
                                      + (kki+1)*32 + quad*8];
    }
    bf16x8 a[4];
#pragma unroll
    for (int t = 0; t < 4; t++)
      a[t] = *(const bf16x8*)&ldsS[swzT(t*16 + l16, kki*32 + quad*8)];
#pragma unroll
    for (int mt = 0; mt < 4; mt++)
#pragma unroll
      for (int nt = 0; nt < 2; nt++)
        acc[mt][nt] = __builtin_amdgcn_mfma_f32_16x16x32_bf16(a[mt], bc[nt], acc[mt][nt], 0, 0, 0);
  }
  __syncthreads();   // #2: GEMM1 LDS reads done -> reuse ldsS (pitch 128)

#pragma unroll
  for (int nt = 0; nt < 2; nt++) {
    const int col = wn + nt*16 + l16;
    const float bz = b2[col];
#pragma unroll
    for (int mt = 0; mt < 4; mt++) {
      const int rowb = mt*16 + quad*4;
#pragma unroll
      for (int rr = 0; rr < 4; rr++)
        ldsS[swzA(rowb+rr, col)] = f2bf(ssp_f(acc[mt][nt][rr] + bz));
    }
  }

  // prefetch GEMM2 B group 0 (independent of LDS)
  bf16x8 b3n[2];
#pragma unroll
  for (int nt = 0; nt < 2; nt++)
    b3n[nt] = *(const bf16x8*)&L3h[(size_t)(wn + nt*16 + l16) * HC + quad*8];

  __syncthreads();   // #3

  f4v acc2[4][2];
#pragma unroll
  for (int i = 0; i < 4; i++) { acc2[i][0] = zf; acc2[i][1] = zf; }

  for (int kki = 0; kki < 4; kki++) {
    bf16x8 bc[2] = {b3n[0], b3n[1]};
    if (kki < 3) {
#pragma unroll
      for (int nt = 0; nt < 2; nt++)
        b3n[nt] = *(const bf16x8*)&L3h[(size_t)(wn + nt*16 + l16) * HC
                                       + (kki+1)*32 + quad*8];
    }
    bf16x8 a[4];
#pragma unroll
    for (int t = 0; t < 4; t++)
      a[t] = *(const bf16x8*)&ldsS[swzA(t*16 + l16, kki*32 + quad*8)];
#pragma unroll
    for (int mt = 0; mt < 4; mt++)
#pragma unroll
      for (int nt = 0; nt < 2; nt++)
        acc2[mt][nt] = __builtin_amdgcn_mfma_f32_16x16x32_bf16(a[mt], bc[nt], acc2[mt][nt], 0, 0, 0);
  }

#pragma unroll
  for (int nt = 0; nt < 2; nt++) {
    const int ncol = wn + nt*16 + l16;
    const float bz = b3[ncol];
#pragma unroll
    for (int mt = 0; mt < 4; mt++) {
      const int mb = mt*16 + quad*4;
#pragma unroll
      for (int rr = 0; rr < 4; rr++) {
        const int m = m0 + mb + rr;
        if (m < N_NODES) {
          const size_t idx = (size_t)m * HC + ncol;
          h[idx] = f2bf(fmaxf(acc2[mt][nt][rr] + bz, 0.f) + bf2f(h[idx]));
        }
      }
    }
  }
}

// ---------------------------------------------------------------------------
// Fused edge-projection (layer 0) / edge-MLP (layers>0) + lin1 + filter MLP
// + run-reduced scatter. r10 structure (nt-half phases 2+3).
// ea staging (layers>0) uses global_load_lds: LINEAR LDS dest + pre-swizzled
// global source (source perm == swzA read perm, rule both-sides-or-neither).
__device__ __forceinline__ int sigma_row(int r) {
  return ((r >> 2) & 3) * 16 + (r >> 4) * 4 + (r & 3);
}
__global__ __launch_bounds__(256, 3) void emffs_kernel(
    unsigned short* eaP,
    const unsigned short* __restrict__ emWh, const float* __restrict__ emB,
    const unsigned short* __restrict__ l1h,
    const unsigned short* __restrict__ fw1h, const float* __restrict__ fb1,
    const unsigned short* __restrict__ fw2h, const float* __restrict__ fb2,
    const int* __restrict__ eiPs, const int* __restrict__ eiPd,
    const unsigned short* __restrict__ hfeat, float* __restrict__ agg,
    const float* __restrict__ eattr, const float* __restrict__ edgew,
    const int* __restrict__ perm,
    const int do_em, const int do_wb)
{
  __shared__ unsigned short ldsA[64 * 128];   // ea (updated in place), later h stage
  __shared__ unsigned short ldsT[64 * 256];   // em hsum (front, swzA) -> T buffer (swzT)
  __shared__ int sD[64];
  unsigned short* ldsH = ldsT;                // hsum view, pitch-128 swzA

  const int tid  = threadIdx.x;
  const int m0   = blockIdx.x * 64;
  const int lane = tid & 63, wave = tid >> 6;
  const int quad = lane >> 4, l16 = lane & 15;
  const int r = tid >> 2, cb = (tid & 3) * 32;
  const int sp = m0 + sigma_row(r);

  // h[src] gather: used for em hsum now AND hacc in phase 3
  const int s = eiPs[sp];
  bf16x8 hreg[4];
  {
    const unsigned short* hp = hfeat + (size_t)s * HC + cb;
#pragma unroll
    for (int q = 0; q < 4; q++) hreg[q] = *(const bf16x8*)(hp + q*8);
  }
  if (tid < 64) sD[tid] = eiPd[m0 + sigma_row(tid)];

  if (do_em) {
    // ---- ea staging via global_load_lds (async, drained by barrier #1) ----
    // wave w instr q covers ldsA bytes [(w*4+q)*1024, +1024) = rows 4(w*4+q)..+3
    // lane l: row_local = l>>4, 16B slot cs = l&15; source slot pre-swizzled.
#pragma unroll
    for (int q = 0; q < 4; q++) {
      const int row = 4*(wave*4 + q) + (lane >> 4);
      const int cs  = lane & 15;
      const int spr = m0 + sigma_row(row);
      const unsigned short* gsrc = eaP + (size_t)spr * HC + ((cs ^ (row & 7)) << 3);
      __builtin_amdgcn_global_load_lds(
          (gu32*)(const void*)gsrc,
          (su32*)(void*)&ldsA[(size_t)(wave*4 + q) * 512], 16, 0, 0);
    }
    // hsum -> ldsH
    const int d = eiPd[sp];
    const unsigned short* dp = hfeat + (size_t)d * HC + cb;
    unsigned short th[32];
#pragma unroll
    for (int q = 0; q < 4; q++) {
      bf16x8 x2 = *(const bf16x8*)(dp + q*8);
#pragma unroll
      for (int j = 0; j < 8; j++) {
        unsigned short a16 = ((const unsigned short*)&hreg[q])[j];
        unsigned short b16 = ((const unsigned short*)&x2)[j];
        th[q*8 + j] = f2bf(bf2f(a16) + bf2f(b16));
      }
    }
#pragma unroll
    for (int q = 0; q < 4; q++)
      *(bf16x8*)&ldsH[swzA(r, cb + q*8)] = *(bf16x8*)&th[q*8];
  } else {
    // ---- layer 0: compute ea = eattr @ ew^T directly; materialize eaP ----
    const int pe = perm[sp];
    const float4 a4 = *(const float4*)(eattr + (size_t)pe * 4);
    unsigned short th[32];
#pragma unroll
    for (int j = 0; j < 32; j++) {
      const float* w4 = edgew + (size_t)(cb + j) * 4;
      th[j] = f2bf(a4.x*w4[0] + a4.y*w4[1] + a4.z*w4[2] + a4.w*w4[3]);
    }
#pragma unroll
    for (int q = 0; q < 4; q++)
      *(bf16x8*)&ldsA[swzA(r, cb + q*8)] = *(bf16x8*)&th[q*8];
    unsigned short* op = eaP + (size_t)sp * HC + cb;
#pragma unroll
    for (int q = 0; q < 4; q++)
      *(bf16x8*)(op + q*8) = *(bf16x8*)&th[q*8];
  }

  const f4v zf = {0.f, 0.f, 0.f, 0.f};

  // em B prefetch group 0 before the barrier
  bf16x8 bn;
  if (do_em)
    bn = *(const bf16x8*)&emWh[(size_t)(wave*32 + l16) * 2*HC + quad*8];

  __syncthreads();                       // #1: ldsA (+ldsH) ready

  if (do_em) {
    // em GEMM: [ea | hsum] @ emW^T, N=128 cols, 4 waves x 32 cols
    f4v eacc[4][2];
#pragma unroll
    for (int mt = 0; mt < 4; mt++) { eacc[mt][0] = zf; eacc[mt][1] = zf; }
#pragma unroll
    for (int g = 0; g < 16; g++) {       // g = nt*8 + hf*4 + ki
      const int nt = g >> 3, hf = (g >> 2) & 1, ki = g & 3;
      bf16x8 bc = bn;
      if (g < 15) {
        const int g1 = g + 1;
        const int nt1 = g1 >> 3, hf1 = (g1 >> 2) & 1, ki1 = g1 & 3;
        bn = *(const bf16x8*)&emWh[(size_t)(wave*32 + nt1*16 + l16) * 2*HC
                                   + hf1*HC + ki1*32 + quad*8];
      }
      const unsigned short* src = hf ? ldsH : ldsA;
#pragma unroll
      for (int mt = 0; mt < 4; mt++) {
        bf16x8 a = *(const bf16x8*)&src[swzA(mt*16 + l16, ki*32 + quad*8)];
        eacc[mt][nt] = __builtin_amdgcn_mfma_f32_16x16x32_bf16(a, bc, eacc[mt][nt], 0, 0, 0);
      }
    }
    // in-place ldsA update: each (row,col) read+written by the SAME thread
#pragma unroll
    for (int nt = 0; nt < 2; nt++) {
      const int col = wave*32 + nt*16 + l16;
      const float bz = emB[col];
#pragma unroll
      for (int mt = 0; mt < 4; mt++) {
        const int rowb = mt*16 + quad*4;
#pragma unroll
        for (int rr = 0; rr < 4; rr++) {
          const int row = rowb + rr;
          ldsA[swzA(row, col)] = f2bf(tanh_f(eacc[mt][nt][rr] + bz)
                                      + bf2f(ldsA[swzA(row, col)]));
        }
      }
    }
    __syncthreads();                     // #2: ldsA updated; ldsH free
    // coalesced writeback of updated ea (dead after the last em layer)
    if (do_wb) {
      unsigned short* op = eaP + (size_t)sp * HC + cb;
#pragma unroll
      for (int q = 0; q < 4; q++)
        *(bf16x8*)(op + q*8) = *(const bf16x8*)&ldsA[swzA(r, cb + q*8)];
    }
  }

  // ---- phase 1: produce ALL T panels (64 MFMA + ssp), no inner barriers ----
  for (int p = 0; p < 4; p++) {
    f4v tacc[4];
#pragma unroll
    for (int mt = 0; mt < 4; mt++) tacc[mt] = zf;
    const size_t b1row = (size_t)(p*64 + wave*16 + l16);
#pragma unroll
    for (int kk = 0; kk < 128; kk += 32) {
      bf16x8 b = *(const bf16x8*)&fw1h[b1row * HC + kk + quad*8];
#pragma unroll
      for (int mt = 0; mt < 4; mt++) {
        bf16x8 a = *(const bf16x8*)&ldsA[swzA(mt*16 + l16, kk + quad*8)];
        tacc[mt] = __builtin_amdgcn_mfma_f32_16x16x32_bf16(a, b, tacc[mt], 0, 0, 0);
      }
    }
    const int col = p*64 + wave*16 + l16;
    const float bz = fb1[col];
#pragma unroll
    for (int mt = 0; mt < 4; mt++) {
      const int rowb = mt*16 + quad*4;
#pragma unroll
      for (int rr = 0; rr < 4; rr++)
        ldsT[swzT(rowb+rr, col)] = f2bf(ssp_f(tacc[mt][rr] + bz));
    }
  }
  __syncthreads();                       // #3: T complete; ldsA dead

  // ---- stage h regs -> ldsA (ldsT untouched) ----
#pragma unroll
  for (int q = 0; q < 4; q++)
    *(bf16x8*)&ldsA[swzA(r, cb + q*8)] = hreg[q];
  __syncthreads();                       // #4: h staged; T still valid

  // ---- phases 2+3 per nt-half: wacc[4][2] (64 MFMA) + hacc[4][2] (32 MFMA)
  //      + scatter. Halves the live accumulator AGPRs vs full [4][4] pair. ----
  for (int hf = 0; hf < 2; hf++) {
    f4v wacc[4][2];
#pragma unroll
    for (int mt = 0; mt < 4; mt++) { wacc[mt][0] = zf; wacc[mt][1] = zf; }

    __builtin_amdgcn_s_setprio(1);
    for (int p = 0; p < 4; p++) {
#pragma unroll
      for (int kc = 0; kc < 2; kc++) {
        bf16x8 a_[4];
#pragma unroll
        for (int mt = 0; mt < 4; mt++)
          a_[mt] = *(const bf16x8*)&ldsT[swzT(mt*16 + l16, p*64 + kc*32 + quad*8)];
#pragma unroll
        for (int nt = 0; nt < 2; nt++) {
          const size_t brow = (size_t)(wave*64 + (hf*2 + nt)*16 + l16);
          bf16x8 b = *(const bf16x8*)&fw2h[brow * NFC + p*64 + kc*32 + quad*8];
#pragma unroll
          for (int mt = 0; mt < 4; mt++)
            wacc[mt][nt] = __builtin_amdgcn_mfma_f32_16x16x32_bf16(a_[mt], b, wacc[mt][nt], 0, 0, 0);
        }
      }
    }

    f4v hacc[4][2];
#pragma unroll
    for (int mt = 0; mt < 4; mt++) { hacc[mt][0] = zf; hacc[mt][1] = zf; }

#pragma unroll
    for (int kk = 0; kk < 128; kk += 32) {
      bf16x8 a_[4];
#pragma unroll
      for (int mt = 0; mt < 4; mt++)
        a_[mt] = *(const bf16x8*)&ldsA[swzA(mt*16 + l16, kk + quad*8)];
#pragma unroll
      for (int nt = 0; nt < 2; nt++) {
        const size_t brow = (size_t)(wave*64 + (hf*2 + nt)*16 + l16);
        bf16x8 b = *(const bf16x8*)&l1h[brow * HC + kk + quad*8];
#pragma unroll
        for (int mt = 0; mt < 4; mt++)
          hacc[mt][nt] = __builtin_amdgcn_mfma_f32_16x16x32_bf16(a_[mt], b, hacc[mt][nt], 0, 0, 0);
      }
    }
    __builtin_amdgcn_s_setprio(0);

    // run-reduced scatter for this half's columns
#pragma unroll
    for (int nt = 0; nt < 2; nt++) {
      const int col = wave*64 + (hf*2 + nt)*16 + l16;
      const float bz = fb2[col];
      float accum = 0.f;
      int prev = -1;
      bool firstrun = true;
#pragma unroll
      for (int mt = 0; mt < 4; mt++) {
#pragma unroll
        for (int rr = 0; rr < 4; rr++) {
          const int prow = mt*16 + quad*4 + rr;
          const int d = sD[prow];
          const float v = (wacc[mt][nt][rr] + bz) * hacc[mt][nt][rr];
          if (d != prev) {
            if (prev >= 0) {
              if (firstrun) atomicAdd(&agg[(size_t)prev * NFC + col], accum);
              else          agg[(size_t)prev * NFC + col] = accum;
              firstrun = false;
            }
            accum = v; prev = d;
          } else {
            accum += v;
          }
        }
      }
      atomicAdd(&agg[(size_t)prev * NFC + col], accum);   // tail run
    }
  }
}

// ---------------------------------------------------------------------------
__global__ __launch_bounds__(256) void poolhead_kernel(
    const int* __restrict__ batch, const unsigned short* __restrict__ h,
    const float* __restrict__ w1, const float* __restrict__ b1,
    const float* __restrict__ w2, const float* __restrict__ b2,
    float* __restrict__ y)
{
  __shared__ float gs[HC];
  __shared__ float red[256];
  const int g = blockIdx.x;
  const int tid = threadIdx.x;

  int lo = 0, hi = N_NODES;
  while (lo < hi) { int m = (lo + hi) >> 1; if (batch[m] < g) lo = m + 1; else hi = m; }
  int lo2 = lo, hi2 = N_NODES;
  while (lo2 < hi2) { int m = (lo2 + hi2) >> 1; if (batch[m] < g + 1) lo2 = m + 1; else hi2 = m; }
  const int cnt = lo2 - lo;

  if (tid < HC) {
    float s = 0.f;
    for (int i = lo; i < lo2; i++) s += bf2f(h[(size_t)i * HC + tid]);
    gs[tid] = s / (float)max(cnt, 1);
  }
  __syncthreads();

  float partial = 0.f;
  for (int f = tid; f < NFFC; f += 256) {
    float acc = b1[f];
    const float* wr = w1 + (size_t)f * HC;
#pragma unroll 8
    for (int k = 0; k < HC; k++) acc = fmaf(gs[k], wr[k], acc);
    float t = 0.5f * acc * (1.0f + erff(acc * 0.70710678118654752440f));
    partial = fmaf(t, w2[f], partial);
  }
  red[tid] = partial;
  __syncthreads();
  for (int s = 128; s > 0; s >>= 1) {
    if (tid < s) red[tid] += red[tid + s];
    __syncthreads();
  }
  if (tid == 0) y[g] = red[0] + b2[0];
}

// ---------------------------------------------------------------------------
extern "C" void kernel_launch(void* const* d_in, const int* in_sizes, int n_in,
                              void* d_out, int out_size, void* d_ws, size_t ws_size,
                              hipStream_t stream) {
  const int*   x     = (const int*)  d_in[0];
  const int*   ei    = (const int*)  d_in[1];
  const float* eattr = (const float*)d_in[2];
  const int*   batch = (const int*)  d_in[3];
  const float* pos   = (const float*)d_in[4];
  const float* vert  = (const float*)d_in[5];
  const float* posw  = (const float*)d_in[6];
  const float* edgew = (const float*)d_in[7];
  const float* fw1   = (const float*)d_in[8];
  const float* fb1   = (const float*)d_in[9];
  const float* fw2   = (const float*)d_in[10];
  const float* fb2   = (const float*)d_in[11];
  const float* l1w   = (const float*)d_in[12];
  const float* l2w   = (const float*)d_in[13];
  const float* l2b   = (const float*)d_in[14];
  const float* l3w   = (const float*)d_in[15];
  const float* l3b   = (const float*)d_in[16];
  const float* emw   = (const float*)d_in[17];
  const float* emb   = (const float*)d_in[18];
  const float* hw1   = (const float*)d_in[19];
  const float* hb1   = (const float*)d_in[20];
  const float* hw2   = (const float*)d_in[21];
  const float* hb2   = (const float*)d_in[22];
  float* out = (float*)d_out;

  char* ws = (char*)d_ws;
  size_t off = 0;
  auto alloc = [&](size_t bytes) { char* p = ws + off; off += (bytes + 511) & ~(size_t)511; return p; };
  unsigned short* eaP = (unsigned short*)alloc((size_t)N_EDGES*HC*2);  // bf16, dst-sorted rows
  unsigned short* h   = (unsigned short*)alloc((size_t)N_NODES*HC*2);  // bf16
  float* agg  = (float*)alloc((size_t)N_NODES*NFC*4);
  int* deg    = (int*)alloc((size_t)(N_NODES+1)*4);
  int* cursor = (int*)alloc((size_t)(N_NODES+1)*4);
  int* bsum   = (int*)alloc((size_t)256*4);
  int* perm   = (int*)alloc((size_t)N_EDGES*4);
  int* eiPs   = (int*)alloc((size_t)N_EDGES*4);
  int* eiPd   = (int*)alloc((size_t)N_EDGES*4);
  const int n_fw1 = NLAYER*NFC*HC, n_fw2 = NLAYER*NFC*NFC, n_l1 = NLAYER*NFC*HC;
  const int n_l2 = NLAYER*HC*NFC, n_l3 = NLAYER*HC*HC, n_em = NLAYER*HC*2*HC;
  unsigned short* fw1h = (unsigned short*)alloc((size_t)n_fw1*2);
  unsigned short* fw2h = (unsigned short*)alloc((size_t)n_fw2*2);
  unsigned short* l1h  = (unsigned short*)alloc((size_t)n_l1*2);
  unsigned short* l2h  = (unsigned short*)alloc((size_t)n_l2*2);
  unsigned short* l3h  = (unsigned short*)alloc((size_t)n_l3*2);
  unsigned short* emh  = (unsigned short*)alloc((size_t)n_em*2);

  const int NSCAN = N_NODES + 1;                 // 50001
  const int NB    = (NSCAN + 255) / 256;         // 196

  zeroi_kernel<<<(NSCAN+255)/256, 256, 0, stream>>>(deg, NSCAN);
  hist_kernel<<<(N_EDGES+255)/256, 256, 0, stream>>>(ei, deg);
  scan1_kernel<<<NB, 256, 0, stream>>>(deg, cursor, bsum, NSCAN);
  scan2_kernel<<<1, 256, 0, stream>>>(bsum, NB);
  scan3_kernel<<<NB, 256, 0, stream>>>(cursor, bsum, NSCAN);
  perm_kernel<<<(N_EDGES+255)/256, 256, 0, stream>>>(ei, cursor, perm);
  eperm_kernel<<<(N_EDGES+255)/256, 256, 0, stream>>>(ei, perm, eiPs, eiPd);

  wconv_kernel<<<(n_fw1+255)/256, 256, 0, stream>>>(fw1, fw1h, n_fw1);
  wconv_kernel<<<(n_fw2+255)/256, 256, 0, stream>>>(fw2, fw2h, n_fw2);
  wconv_kernel<<<(n_l1 +255)/256, 256, 0, stream>>>(l1w, l1h, n_l1);
  wconv_kernel<<<(n_l2 +255)/256, 256, 0, stream>>>(l2w, l2h, n_l2);
  wconv_kernel<<<(n_l3 +255)/256, 256, 0, stream>>>(l3w, l3h, n_l3);
  wconv_kernel<<<(n_em +255)/256, 256, 0, stream>>>(emw, emh, n_em);

  const int GN   = (N_NODES + 63) / 64;     // 782
  const int GE64 = N_EDGES / 64;            // 3125 (exact)

  embed_kernel<<<N_NODES, 128, 0, stream>>>(x, pos, vert, posw, h);
  zero_kernel<<<((N_NODES*NFC/4) + 255)/256, 256, 0, stream>>>(
      (float4*)agg, N_NODES*NFC/4);

  for (int i = 0; i < NLAYER; ++i) {
    const int em_i = (i > 0) ? (i - 1) : 0;
    emffs_kernel<<<GE64, 256, 0, stream>>>(
        eaP,
        emh + (size_t)em_i*HC*2*HC, emb + (size_t)em_i*HC,
        l1h + (size_t)i*NFC*HC,
        fw1h + (size_t)i*NFC*HC, fb1 + (size_t)i*NFC,
        fw2h + (size_t)i*NFC*NFC, fb2 + (size_t)i*NFC,
        eiPs, eiPd, h, agg,
        eattr, edgew, perm,
        (i > 0) ? 1 : 0, (i < NLAYER - 1) ? 1 : 0);
    nodeup_kernel<<<GN, 256, 0, stream>>>(
        agg, l2h + (size_t)i*HC*NFC, l2b + (size_t)i*HC,
        l3h + (size_t)i*HC*HC, l3b + (size_t)i*HC, h);
  }

  poolhead_kernel<<<N_GRAPH, 256, 0, stream>>>(batch, h, hw1, hb1, hw2, hb2, out);
}

// Round 13
// 1347.081 us; speedup vs baseline: 1.0130x; 1.0130x over previous
//
#include <hip/hip_runtime.h>
#include <hip/hip_bf16.h>
#include <math.h>

#define N_NODES 50000
#define N_EDGES 200000
#define N_GRAPH 1024
#define HC      128
#define NFC     256
#define NLAYER  5
#define NFFC    512

typedef short bf16x8 __attribute__((ext_vector_type(8)));
typedef float f4v    __attribute__((ext_vector_type(4)));

__device__ __forceinline__ float ssp_f(float x) {
  float e = __expf(-fabsf(x));
  return fmaxf(x, 0.0f) + __logf(1.0f + e) - 0.69314718055994530942f;
}
__device__ __forceinline__ float tanh_f(float x) {
  float e = __expf(2.0f * fabsf(x));
  float t = 1.0f - 2.0f * __builtin_amdgcn_rcpf(e + 1.0f);
  return copysignf(t, x);
}
__device__ __forceinline__ unsigned short f2bf(float x) {
  union { float f; unsigned u; } v; v.f = x;
  unsigned r = v.u + 0x7fff + ((v.u >> 16) & 1);
  return (unsigned short)(r >> 16);
}
__device__ __forceinline__ float bf2f(unsigned short b) {
  union { unsigned u; float f; } v; v.u = (unsigned)b << 16; return v.f;
}

// XOR 16B-slot swizzle (write and read must both use these).
__device__ __forceinline__ int swzA(int row, int col) {   // 128-short pitch
  return (row << 7) + (((col >> 3) ^ (row & 7)) << 3) + (col & 7);
}
__device__ __forceinline__ int swzT(int row, int col) {   // 256-short pitch
  return (row << 8) + (((col >> 3) ^ (row & 7)) << 3) + (col & 7);
}

// ---------------------------------------------------------------------------
__global__ void zero_kernel(float4* __restrict__ p, int n4) {
  int i = blockIdx.x * blockDim.x + threadIdx.x;
  if (i < n4) p[i] = make_float4(0.f, 0.f, 0.f, 0.f);
}
__global__ void zeroi_kernel(int* __restrict__ p, int n) {
  int i = blockIdx.x * blockDim.x + threadIdx.x;
  if (i < n) p[i] = 0;
}

// ---- dst-sort infrastructure ----------------------------------------------
__global__ void hist_kernel(const int* __restrict__ ei, int* __restrict__ deg) {
  int e = blockIdx.x * blockDim.x + threadIdx.x;
  if (e < N_EDGES) atomicAdd(&deg[ei[N_EDGES + e]], 1);
}
__global__ void scan1_kernel(const int* __restrict__ deg, int* __restrict__ excl,
                             int* __restrict__ bsum, int n) {
  __shared__ int buf[256];
  const int tid = threadIdx.x;
  const int i = blockIdx.x * 256 + tid;
  int v = (i < n) ? deg[i] : 0;
  buf[tid] = v;
  __syncthreads();
  for (int s = 1; s < 256; s <<= 1) {
    int t = (tid >= s) ? buf[tid - s] : 0;
    __syncthreads();
    buf[tid] += t;
    __syncthreads();
  }
  if (i < n) excl[i] = buf[tid] - v;
  if (tid == 255) bsum[blockIdx.x] = buf[255];
}
__global__ void scan2_kernel(int* __restrict__ bsum, int nb) {
  __shared__ int buf[256];
  const int tid = threadIdx.x;
  int v = (tid < nb) ? bsum[tid] : 0;
  buf[tid] = v;
  __syncthreads();
  for (int s = 1; s < 256; s <<= 1) {
    int t = (tid >= s) ? buf[tid - s] : 0;
    __syncthreads();
    buf[tid] += t;
    __syncthreads();
  }
  if (tid < nb) bsum[tid] = buf[tid] - v;
}
__global__ void scan3_kernel(int* __restrict__ excl, const int* __restrict__ bsum, int n) {
  int i = blockIdx.x * 256 + threadIdx.x;
  if (i < n) excl[i] += bsum[blockIdx.x];
}
__global__ void perm_kernel(const int* __restrict__ ei, int* __restrict__ cursor,
                            int* __restrict__ perm) {
  int e = blockIdx.x * blockDim.x + threadIdx.x;
  if (e < N_EDGES) {
    int d = ei[N_EDGES + e];
    int p = atomicAdd(&cursor[d], 1);
    perm[p] = e;
  }
}
__global__ void eperm_kernel(const int* __restrict__ ei, const int* __restrict__ perm,
                             int* __restrict__ eiPs, int* __restrict__ eiPd,
                             int* __restrict__ ipos) {
  int p = blockIdx.x * blockDim.x + threadIdx.x;
  if (p < N_EDGES) {
    int e = perm[p];
    eiPs[p] = ei[e];
    eiPd[p] = ei[N_EDGES + e];
    ipos[e] = p;
  }
}

__global__ void wconv_kernel(const float* __restrict__ w,
                             unsigned short* __restrict__ hi, int n) {
  int i = blockIdx.x * blockDim.x + threadIdx.x;
  if (i < n) hi[i] = f2bf(w[i]);
}

__global__ void embed_kernel(const int* __restrict__ x, const float* __restrict__ pos,
                             const float* __restrict__ vert, const float* __restrict__ posw,
                             unsigned short* __restrict__ h) {
  int n = blockIdx.x;
  int c = threadIdx.x;            // 128 threads
  float v;
  if (c < 80) {
    v = vert[(size_t)x[n] * 80 + c];
  } else {
    int j = c - 80;
    v = pos[n*3+0]*posw[j*3+0] + pos[n*3+1]*posw[j*3+1] + pos[n*3+2]*posw[j*3+2];
  }
  h[(size_t)n*HC + c] = f2bf(v);
}

__global__ void edgeproj_kernel(const float* __restrict__ eattr, const float* __restrict__ ew,
                                unsigned short* __restrict__ eaP,
                                const int* __restrict__ ipos) {
  int idx = blockIdx.x * blockDim.x + threadIdx.x;
  if (idx >= N_EDGES * HC) return;
  int e = idx >> 7, c = idx & 127;
  const float* a = eattr + (size_t)e*4;
  const float* w = ew + (size_t)c*4;
  eaP[(size_t)ipos[e]*HC + c] = f2bf(a[0]*w[0] + a[1]*w[1] + a[2]*w[2] + a[3]*w[3]);
}

// ---------------------------------------------------------------------------
// Node update: 64-row tile (grid 782, 32KB LDS), B-prefetch. (r6 form)
__global__ __launch_bounds__(256, 4) void nodeup_kernel(
    float* __restrict__ agg,
    const unsigned short* __restrict__ L2h,
    const float* __restrict__ b2,
    const unsigned short* __restrict__ L3h,
    const float* __restrict__ b3,
    unsigned short* h)
{
  __shared__ unsigned short ldsS[64 * 256];   // swizzled; reused for ssp out

  const int tid  = threadIdx.x;
  const int m0   = blockIdx.x * 64;
  const int lane = tid & 63, wave = tid >> 6;
  const int quad = lane >> 4, l16 = lane & 15;
  const int wn = wave * 32;           // waves split N only
  const int r  = tid >> 2;            // 0..63
  const int cb2 = (tid & 3) * 64;     // 64-col chunk

  const bool mok = (m0 + r) < N_NODES;

  // stage agg row-chunk -> bf16 LDS, then zero it for the next layer
  if (mok) {
    const float* ap = agg + (size_t)(m0 + r) * NFC + cb2;
#pragma unroll
    for (int g = 0; g < 8; g++) {
      float4 v0 = *(const float4*)(ap + g*8);
      float4 v1 = *(const float4*)(ap + g*8 + 4);
      unsigned short th[8];
      th[0] = f2bf(v0.x); th[1] = f2bf(v0.y); th[2] = f2bf(v0.z); th[3] = f2bf(v0.w);
      th[4] = f2bf(v1.x); th[5] = f2bf(v1.y); th[6] = f2bf(v1.z); th[7] = f2bf(v1.w);
      *(bf16x8*)&ldsS[swzT(r, cb2 + g*8)] = *(bf16x8*)th;
    }
    float4* zp = (float4*)(agg + (size_t)(m0 + r) * NFC + cb2);
    const float4 z4 = make_float4(0.f, 0.f, 0.f, 0.f);
#pragma unroll
    for (int g = 0; g < 16; g++) zp[g] = z4;
  } else {
    const bf16x8 zb = {0, 0, 0, 0, 0, 0, 0, 0};
#pragma unroll
    for (int g = 0; g < 8; g++) *(bf16x8*)&ldsS[swzT(r, cb2 + g*8)] = zb;
  }

  const f4v zf = {0.f, 0.f, 0.f, 0.f};
  f4v acc[4][2];
#pragma unroll
  for (int i = 0; i < 4; i++) { acc[i][0] = zf; acc[i][1] = zf; }

  // prefetch GEMM1 B group 0 (independent of LDS)
  bf16x8 bn[2];
#pragma unroll
  for (int nt = 0; nt < 2; nt++)
    bn[nt] = *(const bf16x8*)&L2h[(size_t)(wn + nt*16 + l16) * NFC + quad*8];

  __syncthreads();   // #1

  // GEMM1: out = agg @ L2^T  (64 MFMA / wave)
  for (int kki = 0; kki < 8; kki++) {
    bf16x8 bc[2] = {bn[0], bn[1]};
    if (kki < 7) {
#pragma unroll
      for (int nt = 0; nt < 2; nt++)
        bn[nt] = *(const bf16x8*)&L2h[(size_t)(wn + nt*16 + l16) * NFC
                                      + (kki+1)*32 + quad*8];
    }
    bf16x8 a[4];
#pragma unroll
    for (int t = 0; t < 4; t++)
      a[t] = *(const bf16x8*)&ldsS[swzT(t*16 + l16, kki*32 + quad*8)];
#pragma unroll
    for (int mt = 0; mt < 4; mt++)
#pragma unroll
      for (int nt = 0; nt < 2; nt++)
        acc[mt][nt] = __builtin_amdgcn_mfma_f32_16x16x32_bf16(a[mt], bc[nt], acc[mt][nt], 0, 0, 0);
  }
  __syncthreads();   // #2: GEMM1 LDS reads done -> reuse ldsS (pitch 128)

#pragma unroll
  for (int nt = 0; nt < 2; nt++) {
    const int col = wn + nt*16 + l16;
    const float bz = b2[col];
#pragma unroll
    for (int mt = 0; mt < 4; mt++) {
      const int rowb = mt*16 + quad*4;
#pragma unroll
      for (int rr = 0; rr < 4; rr++)
        ldsS[swzA(rowb+rr, col)] = f2bf(ssp_f(acc[mt][nt][rr] + bz));
    }
  }

  // prefetch GEMM2 B group 0 (independent of LDS)
  bf16x8 b3n[2];
#pragma unroll
  for (int nt = 0; nt < 2; nt++)
    b3n[nt] = *(const bf16x8*)&L3h[(size_t)(wn + nt*16 + l16) * HC + quad*8];

  __syncthreads();   // #3

  f4v acc2[4][2];
#pragma unroll
  for (int i = 0; i < 4; i++) { acc2[i][0] = zf; acc2[i][1] = zf; }

  for (int kki = 0; kki < 4; kki++) {
    bf16x8 bc[2] = {b3n[0], b3n[1]};
    if (kki < 3) {
#pragma unroll
      for (int nt = 0; nt < 2; nt++)
        b3n[nt] = *(const bf16x8*)&L3h[(size_t)(wn + nt*16 + l16) * HC
                                       + (kki+1)*32 + quad*8];
    }
    bf16x8 a[4];
#pragma unroll
    for (int t = 0; t < 4; t++)
      a[t] = *(const bf16x8*)&ldsS[swzA(t*16 + l16, kki*32 + quad*8)];
#pragma unroll
    for (int mt = 0; mt < 4; mt++)
#pragma unroll
      for (int nt = 0; nt < 2; nt++)
        acc2[mt][nt] = __builtin_amdgcn_mfma_f32_16x16x32_bf16(a[mt], bc[nt], acc2[mt][nt], 0, 0, 0);
  }

#pragma unroll
  for (int nt = 0; nt < 2; nt++) {
    const int ncol = wn + nt*16 + l16;
    const float bz = b3[ncol];
#pragma unroll
    for (int mt = 0; mt < 4; mt++) {
      const int mb = mt*16 + quad*4;
#pragma unroll
      for (int rr = 0; rr < 4; rr++) {
        const int m = m0 + mb + rr;
        if (m < N_NODES) {
          const size_t idx = (size_t)m * HC + ncol;
          h[idx] = f2bf(fmaxf(acc2[mt][nt][rr] + bz, 0.f) + bf2f(h[idx]));
        }
      }
    }
  }
}

// ---------------------------------------------------------------------------
// Fused edge-MLP (optional prologue) + lin1 + filter MLP + run-reduced scatter.
// nt-half phases 2+3: per half, consume ALL T panels into wacc[4][2], then
// hacc[4][2], then scatter. Peak live accumulator AGPRs 128 -> 64.
__device__ __forceinline__ int sigma_row(int r) {
  return ((r >> 2) & 3) * 16 + (r >> 4) * 4 + (r & 3);
}
__global__ __launch_bounds__(256, 3) void emffs_kernel(
    unsigned short* eaP,
    const unsigned short* __restrict__ emWh, const float* __restrict__ emB,
    const unsigned short* __restrict__ l1h,
    const unsigned short* __restrict__ fw1h, const float* __restrict__ fb1,
    const unsigned short* __restrict__ fw2h, const float* __restrict__ fb2,
    const int* __restrict__ eiPs, const int* __restrict__ eiPd,
    const unsigned short* __restrict__ hfeat, float* __restrict__ agg,
    const int do_em)
{
  __shared__ unsigned short ldsA[64 * 128];   // ea (updated in place), later h stage
  __shared__ unsigned short ldsT[64 * 256];   // em hsum (front, swzA) -> T buffer (swzT)
  __shared__ int sD[64];
  unsigned short* ldsH = ldsT;                // hsum view, pitch-128 swzA

  const int tid  = threadIdx.x;
  const int m0   = blockIdx.x * 64;
  const int lane = tid & 63, wave = tid >> 6;
  const int quad = lane >> 4, l16 = lane & 15;
  const int r = tid >> 2, cb = (tid & 3) * 32;
  const int sp = m0 + sigma_row(r);

  // h[src] gather: used for em hsum now AND hacc in phase 3
  const int s = eiPs[sp];
  bf16x8 hreg[4];
  {
    const unsigned short* hp = hfeat + (size_t)s * HC + cb;
#pragma unroll
    for (int q = 0; q < 4; q++) hreg[q] = *(const bf16x8*)(hp + q*8);
  }
  if (tid < 64) sD[tid] = eiPd[m0 + sigma_row(tid)];

  // stage ea tile: contiguous sorted rows, no indirection
  {
    const unsigned short* ap = eaP + (size_t)sp * HC + cb;
#pragma unroll
    for (int q = 0; q < 4; q++)
      *(bf16x8*)&ldsA[swzA(r, cb + q*8)] = *(const bf16x8*)(ap + q*8);
  }

  if (do_em) {
    const int d = eiPd[sp];
    const unsigned short* dp = hfeat + (size_t)d * HC + cb;
    unsigned short th[32];
#pragma unroll
    for (int q = 0; q < 4; q++) {
      bf16x8 x2 = *(const bf16x8*)(dp + q*8);
#pragma unroll
      for (int j = 0; j < 8; j++) {
        unsigned short a16 = ((const unsigned short*)&hreg[q])[j];
        unsigned short b16 = ((const unsigned short*)&x2)[j];
        th[q*8 + j] = f2bf(bf2f(a16) + bf2f(b16));
      }
    }
#pragma unroll
    for (int q = 0; q < 4; q++)
      *(bf16x8*)&ldsH[swzA(r, cb + q*8)] = *(bf16x8*)&th[q*8];
  }

  const f4v zf = {0.f, 0.f, 0.f, 0.f};

  // em B prefetch group 0 before the barrier
  bf16x8 bn;
  if (do_em)
    bn = *(const bf16x8*)&emWh[(size_t)(wave*32 + l16) * 2*HC + quad*8];

  __syncthreads();                       // #1: ldsA (+ldsH) ready

  if (do_em) {
    // em GEMM: [ea | hsum] @ emW^T, N=128 cols, 4 waves x 32 cols
    f4v eacc[4][2];
#pragma unroll
    for (int mt = 0; mt < 4; mt++) { eacc[mt][0] = zf; eacc[mt][1] = zf; }
#pragma unroll
    for (int g = 0; g < 16; g++) {       // g = nt*8 + hf*4 + ki
      const int nt = g >> 3, hf = (g >> 2) & 1, ki = g & 3;
      bf16x8 bc = bn;
      if (g < 15) {
        const int g1 = g + 1;
        const int nt1 = g1 >> 3, hf1 = (g1 >> 2) & 1, ki1 = g1 & 3;
        bn = *(const bf16x8*)&emWh[(size_t)(wave*32 + nt1*16 + l16) * 2*HC
                                   + hf1*HC + ki1*32 + quad*8];
      }
      const unsigned short* src = hf ? ldsH : ldsA;
#pragma unroll
      for (int mt = 0; mt < 4; mt++) {
        bf16x8 a = *(const bf16x8*)&src[swzA(mt*16 + l16, ki*32 + quad*8)];
        eacc[mt][nt] = __builtin_amdgcn_mfma_f32_16x16x32_bf16(a, bc, eacc[mt][nt], 0, 0, 0);
      }
    }
    // in-place ldsA update: each (row,col) read+written by the SAME thread
#pragma unroll
    for (int nt = 0; nt < 2; nt++) {
      const int col = wave*32 + nt*16 + l16;
      const float bz = emB[col];
#pragma unroll
      for (int mt = 0; mt < 4; mt++) {
        const int rowb = mt*16 + quad*4;
#pragma unroll
        for (int rr = 0; rr < 4; rr++) {
          const int row = rowb + rr;
          ldsA[swzA(row, col)] = f2bf(tanh_f(eacc[mt][nt][rr] + bz)
                                      + bf2f(ldsA[swzA(row, col)]));
        }
      }
    }
    __syncthreads();                     // #2: ldsA updated; ldsH free
    // coalesced writeback of updated ea (fire-and-forget; overlaps tacc)
    {
      unsigned short* op = eaP + (size_t)sp * HC + cb;
#pragma unroll
      for (int q = 0; q < 4; q++)
        *(bf16x8*)(op + q*8) = *(const bf16x8*)&ldsA[swzA(r, cb + q*8)];
    }
  }

  // ---- phase 1: produce ALL T panels (64 MFMA + ssp), no inner barriers ----
  for (int p = 0; p < 4; p++) {
    f4v tacc[4];
#pragma unroll
    for (int mt = 0; mt < 4; mt++) tacc[mt] = zf;
    const size_t b1row = (size_t)(p*64 + wave*16 + l16);
#pragma unroll
    for (int kk = 0; kk < 128; kk += 32) {
      bf16x8 b = *(const bf16x8*)&fw1h[b1row * HC + kk + quad*8];
#pragma unroll
      for (int mt = 0; mt < 4; mt++) {
        bf16x8 a = *(const bf16x8*)&ldsA[swzA(mt*16 + l16, kk + quad*8)];
        tacc[mt] = __builtin_amdgcn_mfma_f32_16x16x32_bf16(a, b, tacc[mt], 0, 0, 0);
      }
    }
    const int col = p*64 + wave*16 + l16;
    const float bz = fb1[col];
#pragma unroll
    for (int mt = 0; mt < 4; mt++) {
      const int rowb = mt*16 + quad*4;
#pragma unroll
      for (int rr = 0; rr < 4; rr++)
        ldsT[swzT(rowb+rr, col)] = f2bf(ssp_f(tacc[mt][rr] + bz));
    }
  }
  __syncthreads();                       // #3: T complete; ldsA dead

  // ---- stage h regs -> ldsA (ldsT untouched) ----
#pragma unroll
  for (int q = 0; q < 4; q++)
    *(bf16x8*)&ldsA[swzA(r, cb + q*8)] = hreg[q];
  __syncthreads();                       // #4: h staged; T still valid

  // ---- phases 2+3 per nt-half: wacc[4][2] (64 MFMA) + hacc[4][2] (32 MFMA)
  //      + scatter. Halves the live accumulator AGPRs vs full [4][4] pair. ----
  for (int hf = 0; hf < 2; hf++) {
    f4v wacc[4][2];
#pragma unroll
    for (int mt = 0; mt < 4; mt++) { wacc[mt][0] = zf; wacc[mt][1] = zf; }

    __builtin_amdgcn_s_setprio(1);
    for (int p = 0; p < 4; p++) {
#pragma unroll
      for (int kc = 0; kc < 2; kc++) {
        bf16x8 a_[4];
#pragma unroll
        for (int mt = 0; mt < 4; mt++)
          a_[mt] = *(const bf16x8*)&ldsT[swzT(mt*16 + l16, p*64 + kc*32 + quad*8)];
#pragma unroll
        for (int nt = 0; nt < 2; nt++) {
          const size_t brow = (size_t)(wave*64 + (hf*2 + nt)*16 + l16);
          bf16x8 b = *(const bf16x8*)&fw2h[brow * NFC + p*64 + kc*32 + quad*8];
#pragma unroll
          for (int mt = 0; mt < 4; mt++)
            wacc[mt][nt] = __builtin_amdgcn_mfma_f32_16x16x32_bf16(a_[mt], b, wacc[mt][nt], 0, 0, 0);
        }
      }
    }

    f4v hacc[4][2];
#pragma unroll
    for (int mt = 0; mt < 4; mt++) { hacc[mt][0] = zf; hacc[mt][1] = zf; }

#pragma unroll
    for (int kk = 0; kk < 128; kk += 32) {
      bf16x8 a_[4];
#pragma unroll
      for (int mt = 0; mt < 4; mt++)
        a_[mt] = *(const bf16x8*)&ldsA[swzA(mt*16 + l16, kk + quad*8)];
#pragma unroll
      for (int nt = 0; nt < 2; nt++) {
        const size_t brow = (size_t)(wave*64 + (hf*2 + nt)*16 + l16);
        bf16x8 b = *(const bf16x8*)&l1h[brow * HC + kk + quad*8];
#pragma unroll
        for (int mt = 0; mt < 4; mt++)
          hacc[mt][nt] = __builtin_amdgcn_mfma_f32_16x16x32_bf16(a_[mt], b, hacc[mt][nt], 0, 0, 0);
      }
    }
    __builtin_amdgcn_s_setprio(0);

    // run-reduced scatter for this half's columns
#pragma unroll
    for (int nt = 0; nt < 2; nt++) {
      const int col = wave*64 + (hf*2 + nt)*16 + l16;
      const float bz = fb2[col];
      float accum = 0.f;
      int prev = -1;
      bool firstrun = true;
#pragma unroll
      for (int mt = 0; mt < 4; mt++) {
#pragma unroll
        for (int rr = 0; rr < 4; rr++) {
          const int prow = mt*16 + quad*4 + rr;
          const int d = sD[prow];
          const float v = (wacc[mt][nt][rr] + bz) * hacc[mt][nt][rr];
          if (d != prev) {
            if (prev >= 0) {
              if (firstrun) atomicAdd(&agg[(size_t)prev * NFC + col], accum);
              else          agg[(size_t)prev * NFC + col] = accum;
              firstrun = false;
            }
            accum = v; prev = d;
          } else {
            accum += v;
          }
        }
      }
      atomicAdd(&agg[(size_t)prev * NFC + col], accum);   // tail run
    }
  }
}

// ---------------------------------------------------------------------------
__global__ __launch_bounds__(256) void poolhead_kernel(
    const int* __restrict__ batch, const unsigned short* __restrict__ h,
    const float* __restrict__ w1, const float* __restrict__ b1,
    const float* __restrict__ w2, const float* __restrict__ b2,
    float* __restrict__ y)
{
  __shared__ float gs[HC];
  __shared__ float red[256];
  const int g = blockIdx.x;
  const int tid = threadIdx.x;

  int lo = 0, hi = N_NODES;
  while (lo < hi) { int m = (lo + hi) >> 1; if (batch[m] < g) lo = m + 1; else hi = m; }
  int lo2 = lo, hi2 = N_NODES;
  while (lo2 < hi2) { int m = (lo2 + hi2) >> 1; if (batch[m] < g + 1) lo2 = m + 1; else hi2 = m; }
  const int cnt = lo2 - lo;

  if (tid < HC) {
    float s = 0.f;
    for (int i = lo; i < lo2; i++) s += bf2f(h[(size_t)i * HC + tid]);
    gs[tid] = s / (float)max(cnt, 1);
  }
  __syncthreads();

  float partial = 0.f;
  for (int f = tid; f < NFFC; f += 256) {
    float acc = b1[f];
    const float* wr = w1 + (size_t)f * HC;
#pragma unroll 8
    for (int k = 0; k < HC; k++) acc = fmaf(gs[k], wr[k], acc);
    float t = 0.5f * acc * (1.0f + erff(acc * 0.70710678118654752440f));
    partial = fmaf(t, w2[f], partial);
  }
  red[tid] = partial;
  __syncthreads();
  for (int s = 128; s > 0; s >>= 1) {
    if (tid < s) red[tid] += red[tid + s];
    __syncthreads();
  }
  if (tid == 0) y[g] = red[0] + b2[0];
}

// ---------------------------------------------------------------------------
extern "C" void kernel_launch(void* const* d_in, const int* in_sizes, int n_in,
                              void* d_out, int out_size, void* d_ws, size_t ws_size,
                              hipStream_t stream) {
  const int*   x     = (const int*)  d_in[0];
  const int*   ei    = (const int*)  d_in[1];
  const float* eattr = (const float*)d_in[2];
  const int*   batch = (const int*)  d_in[3];
  const float* pos   = (const float*)d_in[4];
  const float* vert  = (const float*)d_in[5];
  const float* posw  = (const float*)d_in[6];
  const float* edgew = (const float*)d_in[7];
  const float* fw1   = (const float*)d_in[8];
  const float* fb1   = (const float*)d_in[9];
  const float* fw2   = (const float*)d_in[10];
  const float* fb2   = (const float*)d_in[11];
  const float* l1w   = (const float*)d_in[12];
  const float* l2w   = (const float*)d_in[13];
  const float* l2b   = (const float*)d_in[14];
  const float* l3w   = (const float*)d_in[15];
  const float* l3b   = (const float*)d_in[16];
  const float* emw   = (const float*)d_in[17];
  const float* emb   = (const float*)d_in[18];
  const float* hw1   = (const float*)d_in[19];
  const float* hb1   = (const float*)d_in[20];
  const float* hw2   = (const float*)d_in[21];
  const float* hb2   = (const float*)d_in[22];
  float* out = (float*)d_out;

  char* ws = (char*)d_ws;
  size_t off = 0;
  auto alloc = [&](size_t bytes) { char* p = ws + off; off += (bytes + 511) & ~(size_t)511; return p; };
  unsigned short* eaP = (unsigned short*)alloc((size_t)N_EDGES*HC*2);  // bf16, dst-sorted rows
  unsigned short* h   = (unsigned short*)alloc((size_t)N_NODES*HC*2);  // bf16
  float* agg  = (float*)alloc((size_t)N_NODES*NFC*4);
  int* deg    = (int*)alloc((size_t)(N_NODES+1)*4);
  int* cursor = (int*)alloc((size_t)(N_NODES+1)*4);
  int* bsum   = (int*)alloc((size_t)256*4);
  int* perm   = (int*)alloc((size_t)N_EDGES*4);
  int* eiPs   = (int*)alloc((size_t)N_EDGES*4);
  int* eiPd   = (int*)alloc((size_t)N_EDGES*4);
  int* ipos   = (int*)alloc((size_t)N_EDGES*4);
  const int n_fw1 = NLAYER*NFC*HC, n_fw2 = NLAYER*NFC*NFC, n_l1 = NLAYER*NFC*HC;
  const int n_l2 = NLAYER*HC*NFC, n_l3 = NLAYER*HC*HC, n_em = NLAYER*HC*2*HC;
  unsigned short* fw1h = (unsigned short*)alloc((size_t)n_fw1*2);
  unsigned short* fw2h = (unsigned short*)alloc((size_t)n_fw2*2);
  unsigned short* l1h  = (unsigned short*)alloc((size_t)n_l1*2);
  unsigned short* l2h  = (unsigned short*)alloc((size_t)n_l2*2);
  unsigned short* l3h  = (unsigned short*)alloc((size_t)n_l3*2);
  unsigned short* emh  = (unsigned short*)alloc((size_t)n_em*2);

  const int NSCAN = N_NODES + 1;                 // 50001
  const int NB    = (NSCAN + 255) / 256;         // 196

  zeroi_kernel<<<(NSCAN+255)/256, 256, 0, stream>>>(deg, NSCAN);
  hist_kernel<<<(N_EDGES+255)/256, 256, 0, stream>>>(ei, deg);
  scan1_kernel<<<NB, 256, 0, stream>>>(deg, cursor, bsum, NSCAN);
  scan2_kernel<<<1, 256, 0, stream>>>(bsum, NB);
  scan3_kernel<<<NB, 256, 0, stream>>>(cursor, bsum, NSCAN);
  perm_kernel<<<(N_EDGES+255)/256, 256, 0, stream>>>(ei, cursor, perm);
  eperm_kernel<<<(N_EDGES+255)/256, 256, 0, stream>>>(ei, perm, eiPs, eiPd, ipos);

  wconv_kernel<<<(n_fw1+255)/256, 256, 0, stream>>>(fw1, fw1h, n_fw1);
  wconv_kernel<<<(n_fw2+255)/256, 256, 0, stream>>>(fw2, fw2h, n_fw2);
  wconv_kernel<<<(n_l1 +255)/256, 256, 0, stream>>>(l1w, l1h, n_l1);
  wconv_kernel<<<(n_l2 +255)/256, 256, 0, stream>>>(l2w, l2h, n_l2);
  wconv_kernel<<<(n_l3 +255)/256, 256, 0, stream>>>(l3w, l3h, n_l3);
  wconv_kernel<<<(n_em +255)/256, 256, 0, stream>>>(emw, emh, n_em);

  const int GN   = (N_NODES + 63) / 64;     // 782
  const int GE64 = N_EDGES / 64;            // 3125 (exact)

  embed_kernel<<<N_NODES, 128, 0, stream>>>(x, pos, vert, posw, h);
  edgeproj_kernel<<<(N_EDGES*HC + 255)/256, 256, 0, stream>>>(eattr, edgew, eaP, ipos);
  zero_kernel<<<((N_NODES*NFC/4) + 255)/256, 256, 0, stream>>>(
      (float4*)agg, N_NODES*NFC/4);

  for (int i = 0; i < NLAYER; ++i) {
    const int em_i = (i > 0) ? (i - 1) : 0;
    emffs_kernel<<<GE64, 256, 0, stream>>>(
        eaP,
        emh + (size_t)em_i*HC*2*HC, emb + (size_t)em_i*HC,
        l1h + (size_t)i*NFC*HC,
        fw1h + (size_t)i*NFC*HC, fb1 + (size_t)i*NFC,
        fw2h + (size_t)i*NFC*NFC, fb2 + (size_t)i*NFC,
        eiPs, eiPd, h, agg, (i > 0) ? 1 : 0);
    nodeup_kernel<<<GN, 256, 0, stream>>>(
        agg, l2h + (size_t)i*HC*NFC, l2b + (size_t)i*HC,
        l3h + (size_t)i*HC*HC, l3b + (size_t)i*HC, h);
  }

  poolhead_kernel<<<N_GRAPH, 256, 0, stream>>>(batch, h, hw1, hb1, hw2, hb2, out);
}